// Round 6
// baseline (324.065 us; speedup 1.0000x reference)
//
#include <hip/hip_runtime.h>
#include <hip/hip_bf16.h>

#define N_ATOMS 30000
#define M_NBR   12
#define A_DIM   256
#define B_DIM   128

typedef __bf16 bf16x8 __attribute__((ext_vector_type(8)));
typedef float  f32x4  __attribute__((ext_vector_type(4)));

// pack 2 f32 -> 2 bf16 (RNE): compiler emits v_cvt_pk_bf16_f32 (1 inst)
__device__ __forceinline__ unsigned pkbf(float a, float b) {
    union { __bf16 h[2]; unsigned u; } r;
    r.h[0] = (__bf16)a; r.h[1] = (__bf16)b;
    return r.u;
}
__device__ __forceinline__ unsigned short f2bf(float f) {
    union { __bf16 h; unsigned short s; } r; r.h = (__bf16)f; return r.s;
}
// bf16 pair -> f32, 1 bitop each
__device__ __forceinline__ float bflo(unsigned u) { union { unsigned x; float f; } v; v.x = u << 16;          return v.f; }
__device__ __forceinline__ float bfhi(unsigned u) { union { unsigned x; float f; } v; v.x = u & 0xffff0000u;  return v.f; }

// packed per-row address for z-column c (0..511):
// layout [band:8][l15:16][slot:4]; band=(c&255)>>5, slot=bit4(c&255)+2*(c>=256).
// Consumer lane (wc,l15) reads its 4 values (2 gate + 2 core) as ONE 8B uint2.
__device__ __forceinline__ int packAddr8(int c) {
    int cc = c & 255;
    int slot = ((cc >> 4) & 1) + ((c >> 8) << 1);
    return (cc >> 5) * 64 + (cc & 15) * 4 + slot;
}

// ---------------- Kernel 0: pack fc_w into bf16 fragment-order tables ----------
__global__ void pack_weights(const float* __restrict__ fc_w,
                             unsigned short* __restrict__ Wp1,
                             unsigned short* __restrict__ Wp3) {
    int idx = blockIdx.x * 256 + threadIdx.x;
    const int n1 = 32 * 1024 * 8;
    if (idx < n1) {
        int j = idx & 7, n = (idx >> 3) & 1023, g = idx >> 13;
        float v = (n < 512) ? fc_w[n * 640 + g * 8 + j]
                            : fc_w[(n - 512) * 640 + 256 + g * 8 + j];
        Wp1[idx] = f2bf(v);
    } else {
        int k = idx - n1;
        if (k < 16 * 512 * 8) {
            int j = k & 7, n = (k >> 3) & 511, g = k >> 12;
            Wp3[k] = f2bf(fc_w[n * 640 + 512 + g * 8 + j]);
        }
    }
}

// ---------------- Kernel 1: P1 = W1*atom + b, P2 = W2*atom, stored PACKED (bf16) ---
// P row (1024 ushorts): [0:512) = P1 packed (packAddr8), [512:1024) = P2 packed.
__global__ __launch_bounds__(512, 2) void gemm_p(
    const float* __restrict__ atom, const float* __restrict__ fc_b,
    const unsigned short* __restrict__ Wp1, unsigned short* __restrict__ P)
{
    __shared__ unsigned short sA[128 * 256];   // 64KB, swizzled bf16 A-tile
    const int tid = threadIdx.x;
    const int r0 = blockIdx.x * 128;
    const int cb = blockIdx.y;                 // 0: W1 half (+bias), 1: W2 half

    #pragma unroll
    for (int s = 0; s < 8; ++s) {
        int G = tid + s * 512;
        int row = G >> 5, gc = G & 31;
        int grow = r0 + row;
        uint4 pk;
        if (grow < N_ATOMS) {
            const float4* src = reinterpret_cast<const float4*>(atom + (size_t)grow * 256 + gc * 8);
            float4 v0 = src[0], v1 = src[1];
            pk.x = pkbf(v0.x, v0.y); pk.y = pkbf(v0.z, v0.w);
            pk.z = pkbf(v1.x, v1.y); pk.w = pkbf(v1.z, v1.w);
        } else {
            pk = make_uint4(0u, 0u, 0u, 0u);
        }
        *reinterpret_cast<uint4*>(&sA[row * 256 + ((gc ^ (row & 7)) << 3)]) = pk;
    }
    __syncthreads();

    const int lane = tid & 63, wave = tid >> 6;
    const int wr = wave >> 2, wcc = wave & 3;
    const int l15 = lane & 15, l16 = lane >> 4;

    f32x4 acc[4][8];
    #pragma unroll
    for (int mt = 0; mt < 4; ++mt)
        #pragma unroll
        for (int nt = 0; nt < 8; ++nt) acc[mt][nt] = f32x4{0.f, 0.f, 0.f, 0.f};

    #pragma unroll
    for (int ks = 0; ks < 8; ++ks) {
        bf16x8 af[4];
        #pragma unroll
        for (int mt = 0; mt < 4; ++mt) {
            int row = wr * 64 + mt * 16 + l15;
            int g = ks * 4 + l16;
            af[mt] = *reinterpret_cast<const bf16x8*>(&sA[row * 256 + ((g ^ (row & 7)) << 3)]);
        }
        bf16x8 bfr[8];
        #pragma unroll
        for (int nt = 0; nt < 8; ++nt) {
            int col = cb * 512 + wcc * 128 + nt * 16 + l15;
            bfr[nt] = *reinterpret_cast<const bf16x8*>(&Wp1[((size_t)(ks * 4 + l16) * 1024 + col) * 8]);
        }
        #pragma unroll
        for (int mt = 0; mt < 4; ++mt)
            #pragma unroll
            for (int nt = 0; nt < 8; ++nt)
                acc[mt][nt] = __builtin_amdgcn_mfma_f32_16x16x32_bf16(af[mt], bfr[nt], acc[mt][nt], 0, 0, 0);
    }

    // epilogue: paired bf16 writes into packed layout (1 cvt_pk + 1 store per pair)
    #pragma unroll
    for (int np = 0; np < 4; ++np) {
        int zc0 = wcc * 128 + np * 32 + l15;     // nt = 2*np ; zc1 = zc0 + 16
        float b0 = (cb == 0) ? fc_b[zc0] : 0.f;
        float b1 = (cb == 0) ? fc_b[zc0 + 16] : 0.f;
        int pa = cb * 512 + packAddr8(zc0);      // even; zc0+16 lands at pa+1
        #pragma unroll
        for (int mt = 0; mt < 4; ++mt) {
            #pragma unroll
            for (int j = 0; j < 4; ++j) {
                int row = r0 + wr * 64 + mt * 16 + l16 * 4 + j;
                if (row < N_ATOMS)
                    *reinterpret_cast<unsigned*>(&P[(size_t)row * 1024 + pa]) =
                        pkbf(acc[mt][2 * np][j] + b0, acc[mt][2 * np + 1][j] + b1);
            }
        }
    }
}

// ---------------- Kernel 2: fused bond-GEMM + gather-add + LN1 + gate*core + mean + LN2 + residual
// 512 threads = 8 waves; 4 atoms (48 rows). Wave wc owns 32 gate cols + 32 core cols.
__global__ __launch_bounds__(512, 4) void fused_conv(
    const float* __restrict__ atom, const float* __restrict__ bond,
    const int* __restrict__ nbr, const unsigned short* __restrict__ P,
    const unsigned short* __restrict__ Wp3,
    const float* __restrict__ ln1_g, const float* __restrict__ ln1_b,
    const float* __restrict__ ln2_g, const float* __restrict__ ln2_b,
    float* __restrict__ out)
{
    __shared__ unsigned short sA[48 * 128];              // 12KB bond tile (bf16, swizzled)
    __shared__ float sRed[2][48][9];                     // padded wave-partials
    __shared__ float2 sStat[48];                         // {rs*L2E, mu*rs*L2E} per row
    __shared__ float sO[4][256];                         // per-atom sum of gate*softplus (log2-scaled)

    const int tid = threadIdx.x;
    const int i0 = blockIdx.x * 4;                       // 7500 blocks exact
    const int lane = tid & 63, wc = tid >> 6;
    const int l15 = lane & 15, l16 = lane >> 4;
    const float L2E = 1.4426950408889634f;

    { float* so = &sO[0][0]; so[tid] = 0.f; so[tid + 512] = 0.f; }

    // ---- 1) neighbor indices FIRST (oldest in vmcnt queue): 3 x int4 (rows l16*4..+3 per mt)
    int4 nbq[3];
    #pragma unroll
    for (int mt = 0; mt < 3; ++mt)
        nbq[mt] = *reinterpret_cast<const int4*>(&nbr[i0 * 12 + mt * 16 + l16 * 4]);

    // ---- 2) bond loads
    float4 bv[2][2];
    #pragma unroll
    for (int s = 0; s < 2; ++s) {
        int G = tid + s * 512;
        if (G < 768) {
            int row = G >> 4, gc = G & 15;
            const float4* src = reinterpret_cast<const float4*>(bond + (size_t)(i0 * 12 + row) * 128 + gc * 8);
            bv[s][0] = src[0]; bv[s][1] = src[1];
        }
    }

    // ---- 3) P2 gathers (wait only on nbq; bond stays in flight) + P1. 32-bit addressing.
    const char* Pb = reinterpret_cast<const char*>(P);
    const unsigned cOff = (unsigned)(wc * 128 + l15 * 8);      // byte offset within packed half-row
    uint2 p2q[12];
    #pragma unroll
    for (int mt = 0; mt < 3; ++mt) {
        const int* nbp = reinterpret_cast<const int*>(&nbq[mt]);
        #pragma unroll
        for (int j = 0; j < 4; ++j)
            p2q[mt * 4 + j] = *reinterpret_cast<const uint2*>(
                Pb + ((unsigned)nbp[j] * 2048u + 1024u + cOff));
    }
    uint2 p1q[3];
    #pragma unroll
    for (int mt = 0; mt < 3; ++mt) {
        unsigned li = (unsigned)((mt * 16 + l16 * 4) / 12);    // j-quads never cross atoms
        p1q[mt] = *reinterpret_cast<const uint2*>(Pb + (((unsigned)i0 + li) * 2048u + cOff));
    }

    // ---- 4) convert + stage bond tile (waits on bond only; gathers stay in flight)
    #pragma unroll
    for (int s = 0; s < 2; ++s) {
        int G = tid + s * 512;
        if (G < 768) {
            int row = G >> 4, gc = G & 15;
            uint4 pk;
            pk.x = pkbf(bv[s][0].x, bv[s][0].y); pk.y = pkbf(bv[s][0].z, bv[s][0].w);
            pk.z = pkbf(bv[s][1].x, bv[s][1].y); pk.w = pkbf(bv[s][1].z, bv[s][1].w);
            *reinterpret_cast<uint4*>(&sA[row * 128 + ((gc ^ (row & 7)) << 3)]) = pk;
        }
    }
    __syncthreads();

    // ---- GEMM: [48,128(bond)] @ Wp3, wave's cols = 32 gate (nt 0,1) + 32 core (nt 2,3) ----
    f32x4 acc[3][4];
    #pragma unroll
    for (int mt = 0; mt < 3; ++mt)
        #pragma unroll
        for (int nt = 0; nt < 4; ++nt) acc[mt][nt] = f32x4{0.f, 0.f, 0.f, 0.f};

    #pragma unroll
    for (int ks = 0; ks < 4; ++ks) {
        bf16x8 af[3];
        #pragma unroll
        for (int mt = 0; mt < 3; ++mt) {
            int row = mt * 16 + l15;
            int g = ks * 4 + l16;
            af[mt] = *reinterpret_cast<const bf16x8*>(&sA[row * 128 + ((g ^ (row & 7)) << 3)]);
        }
        bf16x8 bfr[4];
        #pragma unroll
        for (int nt = 0; nt < 4; ++nt) {
            int col = (nt < 2) ? (wc * 32 + nt * 16 + l15)
                               : (256 + wc * 32 + (nt - 2) * 16 + l15);
            bfr[nt] = *reinterpret_cast<const bf16x8*>(&Wp3[((size_t)(ks * 4 + l16) * 512 + col) * 8]);
        }
        #pragma unroll
        for (int mt = 0; mt < 3; ++mt)
            #pragma unroll
            for (int nt = 0; nt < 4; ++nt)
                acc[mt][nt] = __builtin_amdgcn_mfma_f32_16x16x32_bf16(af[mt], bfr[nt], acc[mt][nt], 0, 0, 0);
    }

    // ---- pass 1: z = acc + P1 + P2 (bitop unpack), LN1 partial stats ----
    #pragma unroll
    for (int mt = 0; mt < 3; ++mt) {
        uint2 c1 = p1q[mt];
        float p1v[4] = { bflo(c1.x), bfhi(c1.x), bflo(c1.y), bfhi(c1.y) };
        #pragma unroll
        for (int j = 0; j < 4; ++j) {
            const int row = mt * 16 + l16 * 4 + j;
            uint2 c2 = p2q[mt * 4 + j];
            float p2v[4] = { bflo(c2.x), bfhi(c2.x), bflo(c2.y), bfhi(c2.y) };
            float s = 0.f, q = 0.f;
            #pragma unroll
            for (int nt = 0; nt < 4; ++nt) {
                float z = acc[mt][nt][j] + p1v[nt] + p2v[nt];
                acc[mt][nt][j] = z;
                s += z; q = fmaf(z, z, q);
            }
            #pragma unroll
            for (int msk = 1; msk <= 8; msk <<= 1) {
                s += __shfl_xor(s, msk, 64);
                q += __shfl_xor(q, msk, 64);
            }
            if (l15 == 0) { sRed[0][row][wc] = s; sRed[1][row][wc] = q; }
        }
    }

    // LN1 affine params (log2e-folded biases) load here: latency hides under barrier+mini-reduce
    float g1[2], gC[2], l2b1[2], l2bC[2];
    #pragma unroll
    for (int nt = 0; nt < 2; ++nt) {
        int a = wc * 32 + nt * 16 + l15;
        g1[nt] = ln1_g[a];       l2b1[nt] = ln1_b[a] * L2E;
        gC[nt] = ln1_g[256 + a]; l2bC[nt] = ln1_b[256 + a] * L2E;
    }
    __syncthreads();

    // ---- mini-reduce: fold 8 wave-partials -> {rs*L2E, mu*rs*L2E} ----
    if (tid < 48) {
        float s4 = 0.f, q4 = 0.f;
        #pragma unroll
        for (int w = 0; w < 8; ++w) { s4 += sRed[0][tid][w]; q4 += sRed[1][tid][w]; }
        float mu = s4 * (1.f / 512.f);
        float var = q4 * (1.f / 512.f) - mu * mu;
        float rs = __builtin_amdgcn_rsqf(var + 1e-5f) * L2E;
        sStat[tid] = make_float2(rs, mu * rs);
    }
    __syncthreads();

    // ---- pass 2: log2-domain sigmoid*softplus; ln2 & 1/12 factors cancel in LN2 (scale-inv) ----
    #pragma unroll
    for (int mt = 0; mt < 3; ++mt) {
        const int li = (mt * 16 + l16 * 4) / 12;
        float2 st[4];
        #pragma unroll
        for (int j = 0; j < 4; ++j) st[j] = sStat[mt * 16 + l16 * 4 + j];
        #pragma unroll
        for (int nt = 0; nt < 2; ++nt) {
            float tq = 0.f;
            #pragma unroll
            for (int j = 0; j < 4; ++j) {
                float ug = fmaf(fmaf(acc[mt][nt][j],     st[j].x, -st[j].y), g1[nt], l2b1[nt]);
                float uc = fmaf(fmaf(acc[mt][nt + 2][j], st[j].x, -st[j].y), gC[nt], l2bC[nt]);
                float gt  = __builtin_amdgcn_rcpf(1.f + exp2f(-ug));
                float sp2 = log2f(1.f + exp2f(uc));
                tq = fmaf(gt, sp2, tq);
            }
            atomicAdd(&sO[li][wc * 32 + nt * 16 + l15], tq);   // 3 contributors per address
        }
    }
    __syncthreads();

    // ---- LN2 + residual (scale-invariant: no /12, no ln2): waves 0..3, one atom each ----
    if (wc < 4) {
        const int gi = i0 + wc;
        float v[4]; float s = 0.f, q = 0.f;
        #pragma unroll
        for (int qd = 0; qd < 4; ++qd) {
            v[qd] = sO[wc][lane + qd * 64];
            s += v[qd]; q = fmaf(v[qd], v[qd], q);
        }
        #pragma unroll
        for (int msk = 1; msk <= 32; msk <<= 1) {
            s += __shfl_xor(s, msk, 64);
            q += __shfl_xor(q, msk, 64);
        }
        float mu = s * (1.f / 256.f);
        float var = q * (1.f / 256.f) - mu * mu;
        float rstd = __builtin_amdgcn_rsqf(var + 1e-5f);
        #pragma unroll
        for (int qd = 0; qd < 4; ++qd) {
            int a = lane + qd * 64;
            out[(size_t)gi * 256 + a] = atom[(size_t)gi * 256 + a]
                                      + (v[qd] - mu) * rstd * ln2_g[a] + ln2_b[a];
        }
    }
}

extern "C" void kernel_launch(void* const* d_in, const int* in_sizes, int n_in,
                              void* d_out, int out_size, void* d_ws, size_t ws_size,
                              hipStream_t stream) {
    const float* atom  = (const float*)d_in[0];
    const float* bond  = (const float*)d_in[1];
    const float* fc_w  = (const float*)d_in[2];
    const float* fc_b  = (const float*)d_in[3];
    const float* ln1_g = (const float*)d_in[4];
    const float* ln1_b = (const float*)d_in[5];
    const float* ln2_g = (const float*)d_in[6];
    const float* ln2_b = (const float*)d_in[7];
    const int*   nbr   = (const int*)d_in[8];

    char* ws = (char*)d_ws;
    unsigned short* P   = (unsigned short*)ws;                          // 61,440,000 B
    unsigned short* Wp1 = (unsigned short*)(ws + 61440000);             // 524,288 B
    unsigned short* Wp3 = (unsigned short*)(ws + 61440000 + 524288);    // 131,072 B
    float* outp = (float*)d_out;

    hipLaunchKernelGGL(pack_weights, dim3(1280), dim3(256), 0, stream, fc_w, Wp1, Wp3);
    hipLaunchKernelGGL(gemm_p, dim3(235, 2), dim3(512), 0, stream, atom, fc_b, Wp1, P);
    hipLaunchKernelGGL(fused_conv, dim3(7500), dim3(512), 0, stream,
                       atom, bond, nbr, P, Wp3, ln1_g, ln1_b, ln2_g, ln2_b, outp);
}

// Round 7
// 286.436 us; speedup vs baseline: 1.1314x; 1.1314x over previous
//
#include <hip/hip_runtime.h>
#include <hip/hip_bf16.h>

#define N_ATOMS 30000
#define M_NBR   12
#define A_DIM   256
#define B_DIM   128

typedef __bf16 bf16x8 __attribute__((ext_vector_type(8)));
typedef float  f32x4  __attribute__((ext_vector_type(4)));

// pack 2 f32 -> 2 bf16 (RNE): compiler emits v_cvt_pk_bf16_f32
__device__ __forceinline__ unsigned pkbf(float a, float b) {
    union { __bf16 h[2]; unsigned u; } r;
    r.h[0] = (__bf16)a; r.h[1] = (__bf16)b;
    return r.u;
}
__device__ __forceinline__ unsigned short f2bf(float f) {
    union { __bf16 h; unsigned short s; } r; r.h = (__bf16)f; return r.s;
}
// bf16 pair -> f32, 1 bitop each
__device__ __forceinline__ float bflo(unsigned u) { union { unsigned x; float f; } v; v.x = u << 16;          return v.f; }
__device__ __forceinline__ float bfhi(unsigned u) { union { unsigned x; float f; } v; v.x = u & 0xffff0000u;  return v.f; }

// full-rate VALU reduce over the 16-lane row axis (cyclic rotate-accumulate).
// After 4 steps every lane in the row-of-16 holds the row sum.
__device__ __forceinline__ float rowsum16(float x) {
    union { float f; int i; } a, b;
    a.f = x;
    b.i = __builtin_amdgcn_update_dpp(0, a.i, 0x121, 0xF, 0xF, false); a.f += b.f; // row_ror:1
    b.i = __builtin_amdgcn_update_dpp(0, a.i, 0x122, 0xF, 0xF, false); a.f += b.f; // row_ror:2
    b.i = __builtin_amdgcn_update_dpp(0, a.i, 0x124, 0xF, 0xF, false); a.f += b.f; // row_ror:4
    b.i = __builtin_amdgcn_update_dpp(0, a.i, 0x128, 0xF, 0xF, false); a.f += b.f; // row_ror:8
    return a.f;
}

// packed per-row address for z-column c (0..511):
// layout [band:8][l15:16][slot:4]; band=(c&255)>>5, slot=bit4(c&255)+2*(c>=256).
// Consumer lane (wc,l15) reads its 4 values (2 gate + 2 core) as ONE 8B uint2.
__device__ __forceinline__ int packAddr8(int c) {
    int cc = c & 255;
    int slot = ((cc >> 4) & 1) + ((c >> 8) << 1);
    return (cc >> 5) * 64 + (cc & 15) * 4 + slot;
}

// ---------------- Kernel 0: pack fc_w into bf16 fragment-order tables ----------
__global__ void pack_weights(const float* __restrict__ fc_w,
                             unsigned short* __restrict__ Wp1,
                             unsigned short* __restrict__ Wp3) {
    int idx = blockIdx.x * 256 + threadIdx.x;
    const int n1 = 32 * 1024 * 8;
    if (idx < n1) {
        int j = idx & 7, n = (idx >> 3) & 1023, g = idx >> 13;
        float v = (n < 512) ? fc_w[n * 640 + g * 8 + j]
                            : fc_w[(n - 512) * 640 + 256 + g * 8 + j];
        Wp1[idx] = f2bf(v);
    } else {
        int k = idx - n1;
        if (k < 16 * 512 * 8) {
            int j = k & 7, n = (k >> 3) & 511, g = k >> 12;
            Wp3[k] = f2bf(fc_w[n * 640 + 512 + g * 8 + j]);
        }
    }
}

// ---------------- Kernel 1: P1 = W1*atom + b, P2 = W2*atom, stored PACKED (bf16) ---
// P row (1024 ushorts): [0:512) = P1 packed (packAddr8), [512:1024) = P2 packed.
__global__ __launch_bounds__(512, 2) void gemm_p(
    const float* __restrict__ atom, const float* __restrict__ fc_b,
    const unsigned short* __restrict__ Wp1, unsigned short* __restrict__ P)
{
    __shared__ unsigned short sA[128 * 256];   // 64KB, swizzled bf16 A-tile
    const int tid = threadIdx.x;
    const int r0 = blockIdx.x * 128;
    const int cb = blockIdx.y;                 // 0: W1 half (+bias), 1: W2 half

    #pragma unroll
    for (int s = 0; s < 8; ++s) {
        int G = tid + s * 512;
        int row = G >> 5, gc = G & 31;
        int grow = r0 + row;
        uint4 pk;
        if (grow < N_ATOMS) {
            const float4* src = reinterpret_cast<const float4*>(atom + (size_t)grow * 256 + gc * 8);
            float4 v0 = src[0], v1 = src[1];
            pk.x = pkbf(v0.x, v0.y); pk.y = pkbf(v0.z, v0.w);
            pk.z = pkbf(v1.x, v1.y); pk.w = pkbf(v1.z, v1.w);
        } else {
            pk = make_uint4(0u, 0u, 0u, 0u);
        }
        *reinterpret_cast<uint4*>(&sA[row * 256 + ((gc ^ (row & 7)) << 3)]) = pk;
    }
    __syncthreads();

    const int lane = tid & 63, wave = tid >> 6;
    const int wr = wave >> 2, wcc = wave & 3;
    const int l15 = lane & 15, l16 = lane >> 4;

    f32x4 acc[4][8];
    #pragma unroll
    for (int mt = 0; mt < 4; ++mt)
        #pragma unroll
        for (int nt = 0; nt < 8; ++nt) acc[mt][nt] = f32x4{0.f, 0.f, 0.f, 0.f};

    #pragma unroll
    for (int ks = 0; ks < 8; ++ks) {
        bf16x8 af[4];
        #pragma unroll
        for (int mt = 0; mt < 4; ++mt) {
            int row = wr * 64 + mt * 16 + l15;
            int g = ks * 4 + l16;
            af[mt] = *reinterpret_cast<const bf16x8*>(&sA[row * 256 + ((g ^ (row & 7)) << 3)]);
        }
        bf16x8 bfr[8];
        #pragma unroll
        for (int nt = 0; nt < 8; ++nt) {
            int col = cb * 512 + wcc * 128 + nt * 16 + l15;
            bfr[nt] = *reinterpret_cast<const bf16x8*>(&Wp1[((size_t)(ks * 4 + l16) * 1024 + col) * 8]);
        }
        #pragma unroll
        for (int mt = 0; mt < 4; ++mt)
            #pragma unroll
            for (int nt = 0; nt < 8; ++nt)
                acc[mt][nt] = __builtin_amdgcn_mfma_f32_16x16x32_bf16(af[mt], bfr[nt], acc[mt][nt], 0, 0, 0);
    }

    // epilogue: paired bf16 writes into packed layout
    #pragma unroll
    for (int np = 0; np < 4; ++np) {
        int zc0 = wcc * 128 + np * 32 + l15;     // nt = 2*np ; zc1 = zc0 + 16
        float b0 = (cb == 0) ? fc_b[zc0] : 0.f;
        float b1 = (cb == 0) ? fc_b[zc0 + 16] : 0.f;
        int pa = cb * 512 + packAddr8(zc0);      // even; zc0+16 lands at pa+1
        #pragma unroll
        for (int mt = 0; mt < 4; ++mt) {
            #pragma unroll
            for (int j = 0; j < 4; ++j) {
                int row = r0 + wr * 64 + mt * 16 + l16 * 4 + j;
                if (row < N_ATOMS)
                    *reinterpret_cast<unsigned*>(&P[(size_t)row * 1024 + pa]) =
                        pkbf(acc[mt][2 * np][j] + b0, acc[mt][2 * np + 1][j] + b1);
            }
        }
    }
}

// ---------------- Kernel 2: fused bond-GEMM + gather-add + LN1 + gate*core + mean + LN2 + residual
// 512 threads = 8 waves; 4 atoms (48 rows). Wave wc owns 32 gate cols + 32 core cols.
__global__ __launch_bounds__(512, 4) void fused_conv(
    const float* __restrict__ atom, const float* __restrict__ bond,
    const int* __restrict__ nbr, const unsigned short* __restrict__ P,
    const unsigned short* __restrict__ Wp3,
    const float* __restrict__ ln1_g, const float* __restrict__ ln1_b,
    const float* __restrict__ ln2_g, const float* __restrict__ ln2_b,
    float* __restrict__ out)
{
    __shared__ unsigned short sA[48 * 128];              // 12KB bond tile (bf16, swizzled)
    __shared__ float sRed[2][48][9];                     // padded wave-partials
    __shared__ float2 sStat[48];                         // {rs*L2E, mu*rs*L2E} per row
    __shared__ float sO[4][256];                         // per-atom sum of gate*softplus (log2-scaled)

    const int tid = threadIdx.x;
    const int i0 = blockIdx.x * 4;                       // 7500 blocks exact
    const int lane = tid & 63, wc = tid >> 6;
    const int l15 = lane & 15, l16 = lane >> 4;
    const float L2E = 1.4426950408889634f;

    { float* so = &sO[0][0]; so[tid] = 0.f; so[tid + 512] = 0.f; }

    // ---- 1) neighbor indices FIRST (oldest in vmcnt queue)
    int4 nbq0 = *reinterpret_cast<const int4*>(&nbr[i0 * 12 +      l16 * 4]);
    int4 nbq1 = *reinterpret_cast<const int4*>(&nbr[i0 * 12 + 16 + l16 * 4]);
    int4 nbq2 = *reinterpret_cast<const int4*>(&nbr[i0 * 12 + 32 + l16 * 4]);

    // ---- 2) bond loads
    float4 bv[2][2];
    #pragma unroll
    for (int s = 0; s < 2; ++s) {
        int G = tid + s * 512;
        if (G < 768) {
            int row = G >> 4, gc = G & 15;
            const float4* src = reinterpret_cast<const float4*>(bond + (size_t)(i0 * 12 + row) * 128 + gc * 8);
            bv[s][0] = src[0]; bv[s][1] = src[1];
        }
    }

    // ---- 3) P2 gather batch A (mt=0,1 -> 8 loads) + P1 (3). 32-bit addressing.
    const char* Pb = reinterpret_cast<const char*>(P);
    const unsigned cOff = (unsigned)(wc * 128 + l15 * 8);      // byte offset within packed half-row
    uint2 p2qA[8];
    {
        const int* n0 = reinterpret_cast<const int*>(&nbq0);
        const int* n1 = reinterpret_cast<const int*>(&nbq1);
        #pragma unroll
        for (int j = 0; j < 4; ++j) {
            p2qA[j]     = *reinterpret_cast<const uint2*>(Pb + ((unsigned)n0[j] * 2048u + 1024u + cOff));
            p2qA[4 + j] = *reinterpret_cast<const uint2*>(Pb + ((unsigned)n1[j] * 2048u + 1024u + cOff));
        }
    }
    uint2 p1q[3];
    #pragma unroll
    for (int mt = 0; mt < 3; ++mt) {
        unsigned li = (unsigned)((mt * 16 + l16 * 4) / 12);    // j-quads never cross atoms
        p1q[mt] = *reinterpret_cast<const uint2*>(Pb + (((unsigned)i0 + li) * 2048u + cOff));
    }

    // ---- 4) convert + stage bond tile (waits on bond only; gathers stay in flight)
    #pragma unroll
    for (int s = 0; s < 2; ++s) {
        int G = tid + s * 512;
        if (G < 768) {
            int row = G >> 4, gc = G & 15;
            uint4 pk;
            pk.x = pkbf(bv[s][0].x, bv[s][0].y); pk.y = pkbf(bv[s][0].z, bv[s][0].w);
            pk.z = pkbf(bv[s][1].x, bv[s][1].y); pk.w = pkbf(bv[s][1].z, bv[s][1].w);
            *reinterpret_cast<uint4*>(&sA[row * 128 + ((gc ^ (row & 7)) << 3)]) = pk;
        }
    }
    __syncthreads();

    // ---- GEMM: [48,128(bond)] @ Wp3; ks 0-1, then issue gather batch B, then ks 2-3 ----
    f32x4 acc[3][4];
    #pragma unroll
    for (int mt = 0; mt < 3; ++mt)
        #pragma unroll
        for (int nt = 0; nt < 4; ++nt) acc[mt][nt] = f32x4{0.f, 0.f, 0.f, 0.f};

    #pragma unroll
    for (int ks = 0; ks < 2; ++ks) {
        bf16x8 af[3];
        #pragma unroll
        for (int mt = 0; mt < 3; ++mt) {
            int row = mt * 16 + l15;
            int g = ks * 4 + l16;
            af[mt] = *reinterpret_cast<const bf16x8*>(&sA[row * 128 + ((g ^ (row & 7)) << 3)]);
        }
        bf16x8 bfr[4];
        #pragma unroll
        for (int nt = 0; nt < 4; ++nt) {
            int col = (nt < 2) ? (wc * 32 + nt * 16 + l15)
                               : (256 + wc * 32 + (nt - 2) * 16 + l15);
            bfr[nt] = *reinterpret_cast<const bf16x8*>(&Wp3[((size_t)(ks * 4 + l16) * 512 + col) * 8]);
        }
        #pragma unroll
        for (int mt = 0; mt < 3; ++mt)
            #pragma unroll
            for (int nt = 0; nt < 4; ++nt)
                acc[mt][nt] = __builtin_amdgcn_mfma_f32_16x16x32_bf16(af[mt], bfr[nt], acc[mt][nt], 0, 0, 0);
    }

    // gather batch B (mt=2 -> 4 loads); latency hides under ks=2,3
    uint2 p2qB[4];
    {
        const int* n2 = reinterpret_cast<const int*>(&nbq2);
        #pragma unroll
        for (int j = 0; j < 4; ++j)
            p2qB[j] = *reinterpret_cast<const uint2*>(Pb + ((unsigned)n2[j] * 2048u + 1024u + cOff));
    }

    #pragma unroll
    for (int ks = 2; ks < 4; ++ks) {
        bf16x8 af[3];
        #pragma unroll
        for (int mt = 0; mt < 3; ++mt) {
            int row = mt * 16 + l15;
            int g = ks * 4 + l16;
            af[mt] = *reinterpret_cast<const bf16x8*>(&sA[row * 128 + ((g ^ (row & 7)) << 3)]);
        }
        bf16x8 bfr[4];
        #pragma unroll
        for (int nt = 0; nt < 4; ++nt) {
            int col = (nt < 2) ? (wc * 32 + nt * 16 + l15)
                               : (256 + wc * 32 + (nt - 2) * 16 + l15);
            bfr[nt] = *reinterpret_cast<const bf16x8*>(&Wp3[((size_t)(ks * 4 + l16) * 512 + col) * 8]);
        }
        #pragma unroll
        for (int mt = 0; mt < 3; ++mt)
            #pragma unroll
            for (int nt = 0; nt < 4; ++nt)
                acc[mt][nt] = __builtin_amdgcn_mfma_f32_16x16x32_bf16(af[mt], bfr[nt], acc[mt][nt], 0, 0, 0);
    }

    // ---- pass 1: z = acc + P1 + P2, LN1 partial stats via DPP row reduce ----
    #pragma unroll
    for (int mt = 0; mt < 3; ++mt) {
        uint2 c1 = p1q[mt];
        float p1v[4] = { bflo(c1.x), bfhi(c1.x), bflo(c1.y), bfhi(c1.y) };
        #pragma unroll
        for (int j = 0; j < 4; ++j) {
            const int row = mt * 16 + l16 * 4 + j;
            uint2 c2 = (mt < 2) ? p2qA[mt * 4 + j] : p2qB[j];
            float p2v[4] = { bflo(c2.x), bfhi(c2.x), bflo(c2.y), bfhi(c2.y) };
            float s = 0.f, q = 0.f;
            #pragma unroll
            for (int nt = 0; nt < 4; ++nt) {
                float z = acc[mt][nt][j] + p1v[nt] + p2v[nt];
                acc[mt][nt][j] = z;
                s += z; q = fmaf(z, z, q);
            }
            s = rowsum16(s);
            q = rowsum16(q);
            if (l15 == 0) { sRed[0][row][wc] = s; sRed[1][row][wc] = q; }
        }
    }

    // LN1 affine params (log2e-folded biases): latency hides under barrier+mini-reduce
    float g1[2], gC[2], l2b1[2], l2bC[2];
    #pragma unroll
    for (int nt = 0; nt < 2; ++nt) {
        int a = wc * 32 + nt * 16 + l15;
        g1[nt] = ln1_g[a];       l2b1[nt] = ln1_b[a] * L2E;
        gC[nt] = ln1_g[256 + a]; l2bC[nt] = ln1_b[256 + a] * L2E;
    }
    __syncthreads();

    // ---- mini-reduce: fold 8 wave-partials -> {rs*L2E, mu*rs*L2E} ----
    if (tid < 48) {
        float s4 = 0.f, q4 = 0.f;
        #pragma unroll
        for (int w = 0; w < 8; ++w) { s4 += sRed[0][tid][w]; q4 += sRed[1][tid][w]; }
        float mu = s4 * (1.f / 512.f);
        float var = q4 * (1.f / 512.f) - mu * mu;
        float rs = __builtin_amdgcn_rsqf(var + 1e-5f) * L2E;
        sStat[tid] = make_float2(rs, mu * rs);
    }
    __syncthreads();

    // ---- pass 2: log2-domain sigmoid*softplus; ln2 & 1/12 cancel in LN2 (scale-inv) ----
    #pragma unroll
    for (int mt = 0; mt < 3; ++mt) {
        const int li = (mt * 16 + l16 * 4) / 12;
        float2 st[4];
        #pragma unroll
        for (int j = 0; j < 4; ++j) st[j] = sStat[mt * 16 + l16 * 4 + j];
        #pragma unroll
        for (int nt = 0; nt < 2; ++nt) {
            float tq = 0.f;
            #pragma unroll
            for (int j = 0; j < 4; ++j) {
                float ug = fmaf(fmaf(acc[mt][nt][j],     st[j].x, -st[j].y), g1[nt], l2b1[nt]);
                float uc = fmaf(fmaf(acc[mt][nt + 2][j], st[j].x, -st[j].y), gC[nt], l2bC[nt]);
                float gt  = __builtin_amdgcn_rcpf(1.f + exp2f(-ug));
                float sp2 = log2f(1.f + exp2f(uc));
                tq = fmaf(gt, sp2, tq);
            }
            atomicAdd(&sO[li][wc * 32 + nt * 16 + l15], tq);   // 3 contributors per address
        }
    }
    __syncthreads();

    // ---- LN2 + residual (scale-invariant): waves 0..3, one atom each ----
    if (wc < 4) {
        const int gi = i0 + wc;
        float v[4]; float s = 0.f, q = 0.f;
        #pragma unroll
        for (int qd = 0; qd < 4; ++qd) {
            v[qd] = sO[wc][lane + qd * 64];
            s += v[qd]; q = fmaf(v[qd], v[qd], q);
        }
        #pragma unroll
        for (int msk = 1; msk <= 32; msk <<= 1) {
            s += __shfl_xor(s, msk, 64);
            q += __shfl_xor(q, msk, 64);
        }
        float mu = s * (1.f / 256.f);
        float var = q * (1.f / 256.f) - mu * mu;
        float rstd = __builtin_amdgcn_rsqf(var + 1e-5f);
        #pragma unroll
        for (int qd = 0; qd < 4; ++qd) {
            int a = lane + qd * 64;
            out[(size_t)gi * 256 + a] = atom[(size_t)gi * 256 + a]
                                      + (v[qd] - mu) * rstd * ln2_g[a] + ln2_b[a];
        }
    }
}

extern "C" void kernel_launch(void* const* d_in, const int* in_sizes, int n_in,
                              void* d_out, int out_size, void* d_ws, size_t ws_size,
                              hipStream_t stream) {
    const float* atom  = (const float*)d_in[0];
    const float* bond  = (const float*)d_in[1];
    const float* fc_w  = (const float*)d_in[2];
    const float* fc_b  = (const float*)d_in[3];
    const float* ln1_g = (const float*)d_in[4];
    const float* ln1_b = (const float*)d_in[5];
    const float* ln2_g = (const float*)d_in[6];
    const float* ln2_b = (const float*)d_in[7];
    const int*   nbr   = (const int*)d_in[8];

    char* ws = (char*)d_ws;
    unsigned short* P   = (unsigned short*)ws;                          // 61,440,000 B
    unsigned short* Wp1 = (unsigned short*)(ws + 61440000);             // 524,288 B
    unsigned short* Wp3 = (unsigned short*)(ws + 61440000 + 524288);    // 131,072 B
    float* outp = (float*)d_out;

    hipLaunchKernelGGL(pack_weights, dim3(1280), dim3(256), 0, stream, fc_w, Wp1, Wp3);
    hipLaunchKernelGGL(gemm_p, dim3(235, 2), dim3(512), 0, stream, atom, fc_b, Wp1, P);
    hipLaunchKernelGGL(fused_conv, dim3(7500), dim3(512), 0, stream,
                       atom, bond, nbr, P, Wp3, ln1_g, ln1_b, ln2_g, ln2_b, outp);
}

// Round 8
// 274.755 us; speedup vs baseline: 1.1795x; 1.0425x over previous
//
#include <hip/hip_runtime.h>
#include <hip/hip_bf16.h>

#define N_ATOMS 30000
#define M_NBR   12
#define A_DIM   256
#define B_DIM   128

typedef __bf16 bf16x8 __attribute__((ext_vector_type(8)));
typedef float  f32x4  __attribute__((ext_vector_type(4)));

// pack 2 f32 -> 2 bf16 (RNE): compiler emits v_cvt_pk_bf16_f32
__device__ __forceinline__ unsigned pkbf(float a, float b) {
    union { __bf16 h[2]; unsigned u; } r;
    r.h[0] = (__bf16)a; r.h[1] = (__bf16)b;
    return r.u;
}
__device__ __forceinline__ unsigned short f2bf(float f) {
    union { __bf16 h; unsigned short s; } r; r.h = (__bf16)f; return r.s;
}
// bf16 pair -> f32, 1 bitop each
__device__ __forceinline__ float bflo(unsigned u) { union { unsigned x; float f; } v; v.x = u << 16;          return v.f; }
__device__ __forceinline__ float bfhi(unsigned u) { union { unsigned x; float f; } v; v.x = u & 0xffff0000u;  return v.f; }

// full-rate VALU reduce over the 16-lane row axis (cyclic rotate-accumulate).
__device__ __forceinline__ float rowsum16(float x) {
    union { float f; int i; } a, b;
    a.f = x;
    b.i = __builtin_amdgcn_update_dpp(0, a.i, 0x121, 0xF, 0xF, false); a.f += b.f; // row_ror:1
    b.i = __builtin_amdgcn_update_dpp(0, a.i, 0x122, 0xF, 0xF, false); a.f += b.f; // row_ror:2
    b.i = __builtin_amdgcn_update_dpp(0, a.i, 0x124, 0xF, 0xF, false); a.f += b.f; // row_ror:4
    b.i = __builtin_amdgcn_update_dpp(0, a.i, 0x128, 0xF, 0xF, false); a.f += b.f; // row_ror:8
    return a.f;
}

// packed per-row address for z-column c (0..511):
// layout [band:8][l15:16][slot:4]; band=(c&255)>>5, slot=bit4(c&255)+2*(c>=256).
// Consumer lane (wc,l15) reads its 4 values (2 gate + 2 core) as ONE 8B uint2.
__device__ __forceinline__ int packAddr8(int c) {
    int cc = c & 255;
    int slot = ((cc >> 4) & 1) + ((c >> 8) << 1);
    return (cc >> 5) * 64 + (cc & 15) * 4 + slot;
}

// ---------------- Kernel 0: pack fc_w into bf16 fragment-order tables ----------
__global__ void pack_weights(const float* __restrict__ fc_w,
                             unsigned short* __restrict__ Wp1,
                             unsigned short* __restrict__ Wp3) {
    int idx = blockIdx.x * 256 + threadIdx.x;
    const int n1 = 32 * 1024 * 8;
    if (idx < n1) {
        int j = idx & 7, n = (idx >> 3) & 1023, g = idx >> 13;
        float v = (n < 512) ? fc_w[n * 640 + g * 8 + j]
                            : fc_w[(n - 512) * 640 + 256 + g * 8 + j];
        Wp1[idx] = f2bf(v);
    } else {
        int k = idx - n1;
        if (k < 16 * 512 * 8) {
            int j = k & 7, n = (k >> 3) & 511, g = k >> 12;
            Wp3[k] = f2bf(fc_w[n * 640 + 512 + g * 8 + j]);
        }
    }
}

// ---------------- Kernel 1: P1 = W1*atom + b, P2 = W2*atom, stored PACKED (bf16) ---
// P row (1024 ushorts): [0:512) = P1 packed (packAddr8), [512:1024) = P2 packed.
__global__ __launch_bounds__(512, 2) void gemm_p(
    const float* __restrict__ atom, const float* __restrict__ fc_b,
    const unsigned short* __restrict__ Wp1, unsigned short* __restrict__ P)
{
    __shared__ unsigned short sA[128 * 256];   // 64KB, swizzled bf16 A-tile
    const int tid = threadIdx.x;
    const int r0 = blockIdx.x * 128;
    const int cb = blockIdx.y;                 // 0: W1 half (+bias), 1: W2 half

    #pragma unroll
    for (int s = 0; s < 8; ++s) {
        int G = tid + s * 512;
        int row = G >> 5, gc = G & 31;
        int grow = r0 + row;
        uint4 pk;
        if (grow < N_ATOMS) {
            const float4* src = reinterpret_cast<const float4*>(atom + (size_t)grow * 256 + gc * 8);
            float4 v0 = src[0], v1 = src[1];
            pk.x = pkbf(v0.x, v0.y); pk.y = pkbf(v0.z, v0.w);
            pk.z = pkbf(v1.x, v1.y); pk.w = pkbf(v1.z, v1.w);
        } else {
            pk = make_uint4(0u, 0u, 0u, 0u);
        }
        *reinterpret_cast<uint4*>(&sA[row * 256 + ((gc ^ (row & 7)) << 3)]) = pk;
    }
    __syncthreads();

    const int lane = tid & 63, wave = tid >> 6;
    const int wr = wave >> 2, wcc = wave & 3;
    const int l15 = lane & 15, l16 = lane >> 4;

    f32x4 acc[4][8];
    #pragma unroll
    for (int mt = 0; mt < 4; ++mt)
        #pragma unroll
        for (int nt = 0; nt < 8; ++nt) acc[mt][nt] = f32x4{0.f, 0.f, 0.f, 0.f};

    #pragma unroll
    for (int ks = 0; ks < 8; ++ks) {
        bf16x8 af[4];
        #pragma unroll
        for (int mt = 0; mt < 4; ++mt) {
            int row = wr * 64 + mt * 16 + l15;
            int g = ks * 4 + l16;
            af[mt] = *reinterpret_cast<const bf16x8*>(&sA[row * 256 + ((g ^ (row & 7)) << 3)]);
        }
        bf16x8 bfr[8];
        #pragma unroll
        for (int nt = 0; nt < 8; ++nt) {
            int col = cb * 512 + wcc * 128 + nt * 16 + l15;
            bfr[nt] = *reinterpret_cast<const bf16x8*>(&Wp1[((size_t)(ks * 4 + l16) * 1024 + col) * 8]);
        }
        #pragma unroll
        for (int mt = 0; mt < 4; ++mt)
            #pragma unroll
            for (int nt = 0; nt < 8; ++nt)
                acc[mt][nt] = __builtin_amdgcn_mfma_f32_16x16x32_bf16(af[mt], bfr[nt], acc[mt][nt], 0, 0, 0);
    }

    // epilogue: paired bf16 writes into packed layout
    #pragma unroll
    for (int np = 0; np < 4; ++np) {
        int zc0 = wcc * 128 + np * 32 + l15;     // nt = 2*np ; zc1 = zc0 + 16
        float b0 = (cb == 0) ? fc_b[zc0] : 0.f;
        float b1 = (cb == 0) ? fc_b[zc0 + 16] : 0.f;
        int pa = cb * 512 + packAddr8(zc0);      // even; zc0+16 lands at pa+1
        #pragma unroll
        for (int mt = 0; mt < 4; ++mt) {
            #pragma unroll
            for (int j = 0; j < 4; ++j) {
                int row = r0 + wr * 64 + mt * 16 + l16 * 4 + j;
                if (row < N_ATOMS)
                    *reinterpret_cast<unsigned*>(&P[(size_t)row * 1024 + pa]) =
                        pkbf(acc[mt][2 * np][j] + b0, acc[mt][2 * np + 1][j] + b1);
            }
        }
    }
}

// ---------------- Kernel 2: fused bond-GEMM + gather-add + LN1 + gate*core + mean + LN2 + residual
// 512 threads = 8 waves; 4 atoms (48 rows). Wave wc owns 32 gate cols + 32 core cols.
// Key trick: acc is INITIALIZED with P1+P2 before the GEMM (MFMA accumulates bond@W3 on top),
// so the gathered values are dead before the first MFMA -> no register spill at the 128-reg cap.
__global__ __launch_bounds__(512, 4) void fused_conv(
    const float* __restrict__ atom, const float* __restrict__ bond,
    const int* __restrict__ nbr, const unsigned short* __restrict__ P,
    const unsigned short* __restrict__ Wp3,
    const float* __restrict__ ln1_g, const float* __restrict__ ln1_b,
    const float* __restrict__ ln2_g, const float* __restrict__ ln2_b,
    float* __restrict__ out)
{
    __shared__ unsigned short sA[48 * 128];              // 12KB bond tile (bf16, swizzled)
    __shared__ float sRed[2][48][9];                     // padded wave-partials
    __shared__ float2 sStat[48];                         // {rs*L2E, mu*rs*L2E} per row
    __shared__ float sO[4][256];                         // per-atom sum of gate*softplus (log2-scaled)

    const int tid = threadIdx.x;
    const int i0 = blockIdx.x * 4;                       // 7500 blocks exact
    const int lane = tid & 63, wc = tid >> 6;
    const int l15 = lane & 15, l16 = lane >> 4;
    const float L2E = 1.4426950408889634f;

    { float* so = &sO[0][0]; so[tid] = 0.f; so[tid + 512] = 0.f; }

    // ---- 1) neighbor indices FIRST
    int4 nbq0 = *reinterpret_cast<const int4*>(&nbr[i0 * 12 +      l16 * 4]);
    int4 nbq1 = *reinterpret_cast<const int4*>(&nbr[i0 * 12 + 16 + l16 * 4]);
    int4 nbq2 = *reinterpret_cast<const int4*>(&nbr[i0 * 12 + 32 + l16 * 4]);

    // ---- 2) bond loads
    float4 bv[2][2];
    #pragma unroll
    for (int s = 0; s < 2; ++s) {
        int G = tid + s * 512;
        if (G < 768) {
            int row = G >> 4, gc = G & 15;
            const float4* src = reinterpret_cast<const float4*>(bond + (size_t)(i0 * 12 + row) * 128 + gc * 8);
            bv[s][0] = src[0]; bv[s][1] = src[1];
        }
    }

    // ---- 3) ALL P2 gathers (12) + P1 (3). 32-bit addressing; consumed before the GEMM.
    const char* Pb = reinterpret_cast<const char*>(P);
    const unsigned cOff = (unsigned)(wc * 128 + l15 * 8);      // byte offset within packed half-row
    uint2 p2q[12];
    {
        const int* n0 = reinterpret_cast<const int*>(&nbq0);
        const int* n1 = reinterpret_cast<const int*>(&nbq1);
        const int* n2 = reinterpret_cast<const int*>(&nbq2);
        #pragma unroll
        for (int j = 0; j < 4; ++j) {
            p2q[j]     = *reinterpret_cast<const uint2*>(Pb + ((unsigned)n0[j] * 2048u + 1024u + cOff));
            p2q[4 + j] = *reinterpret_cast<const uint2*>(Pb + ((unsigned)n1[j] * 2048u + 1024u + cOff));
            p2q[8 + j] = *reinterpret_cast<const uint2*>(Pb + ((unsigned)n2[j] * 2048u + 1024u + cOff));
        }
    }
    uint2 p1q[3];
    #pragma unroll
    for (int mt = 0; mt < 3; ++mt) {
        unsigned li = (unsigned)((mt * 16 + l16 * 4) / 12);    // j-quads never cross atoms
        p1q[mt] = *reinterpret_cast<const uint2*>(Pb + (((unsigned)i0 + li) * 2048u + cOff));
    }

    // ---- 4) convert + stage bond tile (waits on bond only; gathers stay in flight)
    #pragma unroll
    for (int s = 0; s < 2; ++s) {
        int G = tid + s * 512;
        if (G < 768) {
            int row = G >> 4, gc = G & 15;
            uint4 pk;
            pk.x = pkbf(bv[s][0].x, bv[s][0].y); pk.y = pkbf(bv[s][0].z, bv[s][0].w);
            pk.z = pkbf(bv[s][1].x, bv[s][1].y); pk.w = pkbf(bv[s][1].z, bv[s][1].w);
            *reinterpret_cast<uint4*>(&sA[row * 128 + ((gc ^ (row & 7)) << 3)]) = pk;
        }
    }

    // ---- 5) acc := P1 + P2 (gathered values die here, before the GEMM)
    f32x4 acc[3][4];
    #pragma unroll
    for (int mt = 0; mt < 3; ++mt) {
        uint2 c1 = p1q[mt];
        float p1v[4] = { bflo(c1.x), bfhi(c1.x), bflo(c1.y), bfhi(c1.y) };
        #pragma unroll
        for (int j = 0; j < 4; ++j) {
            uint2 c2 = p2q[mt * 4 + j];
            acc[mt][0][j] = p1v[0] + bflo(c2.x);
            acc[mt][1][j] = p1v[1] + bfhi(c2.x);
            acc[mt][2][j] = p1v[2] + bflo(c2.y);
            acc[mt][3][j] = p1v[3] + bfhi(c2.y);
        }
    }
    __syncthreads();

    // ---- GEMM: acc += [48,128(bond)] @ Wp3; wave's cols = 32 gate (nt 0,1) + 32 core (nt 2,3)
    #pragma unroll
    for (int ks = 0; ks < 4; ++ks) {
        bf16x8 af[3];
        #pragma unroll
        for (int mt = 0; mt < 3; ++mt) {
            int row = mt * 16 + l15;
            int g = ks * 4 + l16;
            af[mt] = *reinterpret_cast<const bf16x8*>(&sA[row * 128 + ((g ^ (row & 7)) << 3)]);
        }
        bf16x8 bfr[4];
        #pragma unroll
        for (int nt = 0; nt < 4; ++nt) {
            int col = (nt < 2) ? (wc * 32 + nt * 16 + l15)
                               : (256 + wc * 32 + (nt - 2) * 16 + l15);
            bfr[nt] = *reinterpret_cast<const bf16x8*>(&Wp3[((size_t)(ks * 4 + l16) * 512 + col) * 8]);
        }
        #pragma unroll
        for (int mt = 0; mt < 3; ++mt)
            #pragma unroll
            for (int nt = 0; nt < 4; ++nt)
                acc[mt][nt] = __builtin_amdgcn_mfma_f32_16x16x32_bf16(af[mt], bfr[nt], acc[mt][nt], 0, 0, 0);
    }

    // ---- pass 1: LN1 partial stats (stats only; adds already folded into acc) ----
    #pragma unroll
    for (int mt = 0; mt < 3; ++mt) {
        #pragma unroll
        for (int j = 0; j < 4; ++j) {
            const int row = mt * 16 + l16 * 4 + j;
            float z0 = acc[mt][0][j], z1 = acc[mt][1][j];
            float z2 = acc[mt][2][j], z3 = acc[mt][3][j];
            float s = (z0 + z1) + (z2 + z3);
            float q = fmaf(z0, z0, fmaf(z1, z1, fmaf(z2, z2, z3 * z3)));
            s = rowsum16(s);
            q = rowsum16(q);
            if (l15 == 0) { sRed[0][row][wc] = s; sRed[1][row][wc] = q; }
        }
    }

    // LN1 affine params (log2e-folded biases): latency hides under barrier+mini-reduce
    float g1[2], gC[2], l2b1[2], l2bC[2];
    #pragma unroll
    for (int nt = 0; nt < 2; ++nt) {
        int a = wc * 32 + nt * 16 + l15;
        g1[nt] = ln1_g[a];       l2b1[nt] = ln1_b[a] * L2E;
        gC[nt] = ln1_g[256 + a]; l2bC[nt] = ln1_b[256 + a] * L2E;
    }
    __syncthreads();

    // ---- mini-reduce: fold 8 wave-partials -> {rs*L2E, mu*rs*L2E} ----
    if (tid < 48) {
        float s4 = 0.f, q4 = 0.f;
        #pragma unroll
        for (int w = 0; w < 8; ++w) { s4 += sRed[0][tid][w]; q4 += sRed[1][tid][w]; }
        float mu = s4 * (1.f / 512.f);
        float var = q4 * (1.f / 512.f) - mu * mu;
        float rs = __builtin_amdgcn_rsqf(var + 1e-5f) * L2E;
        sStat[tid] = make_float2(rs, mu * rs);
    }
    __syncthreads();

    // ---- pass 2: log2-domain sigmoid*softplus; ln2 & 1/12 cancel in LN2 (scale-inv) ----
    #pragma unroll
    for (int mt = 0; mt < 3; ++mt) {
        const int li = (mt * 16 + l16 * 4) / 12;
        float2 st[4];
        #pragma unroll
        for (int j = 0; j < 4; ++j) st[j] = sStat[mt * 16 + l16 * 4 + j];
        #pragma unroll
        for (int nt = 0; nt < 2; ++nt) {
            float tq = 0.f;
            #pragma unroll
            for (int j = 0; j < 4; ++j) {
                float ug = fmaf(fmaf(acc[mt][nt][j],     st[j].x, -st[j].y), g1[nt], l2b1[nt]);
                float uc = fmaf(fmaf(acc[mt][nt + 2][j], st[j].x, -st[j].y), gC[nt], l2bC[nt]);
                float gt  = __builtin_amdgcn_rcpf(1.f + exp2f(-ug));
                float sp2 = log2f(1.f + exp2f(uc));
                tq = fmaf(gt, sp2, tq);
            }
            atomicAdd(&sO[li][wc * 32 + nt * 16 + l15], tq);   // 3 contributors per address
        }
    }
    __syncthreads();

    // ---- LN2 + residual (scale-invariant): waves 0..3, one atom each ----
    if (wc < 4) {
        const int gi = i0 + wc;
        float v[4]; float s = 0.f, q = 0.f;
        #pragma unroll
        for (int qd = 0; qd < 4; ++qd) {
            v[qd] = sO[wc][lane + qd * 64];
            s += v[qd]; q = fmaf(v[qd], v[qd], q);
        }
        #pragma unroll
        for (int msk = 1; msk <= 32; msk <<= 1) {
            s += __shfl_xor(s, msk, 64);
            q += __shfl_xor(q, msk, 64);
        }
        float mu = s * (1.f / 256.f);
        float var = q * (1.f / 256.f) - mu * mu;
        float rstd = __builtin_amdgcn_rsqf(var + 1e-5f);
        #pragma unroll
        for (int qd = 0; qd < 4; ++qd) {
            int a = lane + qd * 64;
            out[(size_t)gi * 256 + a] = atom[(size_t)gi * 256 + a]
                                      + (v[qd] - mu) * rstd * ln2_g[a] + ln2_b[a];
        }
    }
}

extern "C" void kernel_launch(void* const* d_in, const int* in_sizes, int n_in,
                              void* d_out, int out_size, void* d_ws, size_t ws_size,
                              hipStream_t stream) {
    const float* atom  = (const float*)d_in[0];
    const float* bond  = (const float*)d_in[1];
    const float* fc_w  = (const float*)d_in[2];
    const float* fc_b  = (const float*)d_in[3];
    const float* ln1_g = (const float*)d_in[4];
    const float* ln1_b = (const float*)d_in[5];
    const float* ln2_g = (const float*)d_in[6];
    const float* ln2_b = (const float*)d_in[7];
    const int*   nbr   = (const int*)d_in[8];

    char* ws = (char*)d_ws;
    unsigned short* P   = (unsigned short*)ws;                          // 61,440,000 B
    unsigned short* Wp1 = (unsigned short*)(ws + 61440000);             // 524,288 B
    unsigned short* Wp3 = (unsigned short*)(ws + 61440000 + 524288);    // 131,072 B
    float* outp = (float*)d_out;

    hipLaunchKernelGGL(pack_weights, dim3(1280), dim3(256), 0, stream, fc_w, Wp1, Wp3);
    hipLaunchKernelGGL(gemm_p, dim3(235, 2), dim3(512), 0, stream, atom, fc_b, Wp1, P);
    hipLaunchKernelGGL(fused_conv, dim3(7500), dim3(512), 0, stream,
                       atom, bond, nbr, P, Wp3, ln1_g, ln1_b, ln2_g, ln2_b, outp);
}

// Round 9
// 272.976 us; speedup vs baseline: 1.1872x; 1.0065x over previous
//
#include <hip/hip_runtime.h>
#include <hip/hip_bf16.h>

#define N_ATOMS 30000
#define M_NBR   12
#define A_DIM   256
#define B_DIM   128

typedef __bf16 bf16x8 __attribute__((ext_vector_type(8)));
typedef float  f32x4  __attribute__((ext_vector_type(4)));

// pack 2 f32 -> 2 bf16 (RNE): compiler emits v_cvt_pk_bf16_f32
__device__ __forceinline__ unsigned pkbf(float a, float b) {
    union { __bf16 h[2]; unsigned u; } r;
    r.h[0] = (__bf16)a; r.h[1] = (__bf16)b;
    return r.u;
}
__device__ __forceinline__ unsigned short f2bf(float f) {
    union { __bf16 h; unsigned short s; } r; r.h = (__bf16)f; return r.s;
}
// bf16 pair -> f32, 1 bitop each
__device__ __forceinline__ float bflo(unsigned u) { union { unsigned x; float f; } v; v.x = u << 16;          return v.f; }
__device__ __forceinline__ float bfhi(unsigned u) { union { unsigned x; float f; } v; v.x = u & 0xffff0000u;  return v.f; }

// raw transcendentals: single v_exp_f32 / v_log_f32 (libm exp2f/log2f go through OCML = ~15-20 insts)
__device__ __forceinline__ float fexp2(float x) { return __builtin_amdgcn_exp2f(x); }
__device__ __forceinline__ float flog2(float x) { return __builtin_amdgcn_logf(x); }

// full-rate VALU reduce over the 16-lane row axis (cyclic rotate-accumulate).
// bound_ctrl=true: rotate has no invalid lanes -> old operand unused -> 1 v_mov_b32_dpp per step.
__device__ __forceinline__ float rowsum16(float x) {
    union { float f; int i; } a, b;
    a.f = x;
    b.i = __builtin_amdgcn_update_dpp(0, a.i, 0x121, 0xF, 0xF, true); a.f += b.f; // row_ror:1
    b.i = __builtin_amdgcn_update_dpp(0, a.i, 0x122, 0xF, 0xF, true); a.f += b.f; // row_ror:2
    b.i = __builtin_amdgcn_update_dpp(0, a.i, 0x124, 0xF, 0xF, true); a.f += b.f; // row_ror:4
    b.i = __builtin_amdgcn_update_dpp(0, a.i, 0x128, 0xF, 0xF, true); a.f += b.f; // row_ror:8
    return a.f;
}

// packed per-row address for z-column c (0..511):
// layout [band:8][l15:16][slot:4]; band=(c&255)>>5, slot=bit4(c&255)+2*(c>=256).
// Consumer lane (wc,l15) reads its 4 values (2 gate + 2 core) as ONE 8B uint2.
__device__ __forceinline__ int packAddr8(int c) {
    int cc = c & 255;
    int slot = ((cc >> 4) & 1) + ((c >> 8) << 1);
    return (cc >> 5) * 64 + (cc & 15) * 4 + slot;
}

// ---------------- Kernel 0: pack fc_w into bf16 fragment-order tables ----------
__global__ void pack_weights(const float* __restrict__ fc_w,
                             unsigned short* __restrict__ Wp1,
                             unsigned short* __restrict__ Wp3) {
    int idx = blockIdx.x * 256 + threadIdx.x;
    const int n1 = 32 * 1024 * 8;
    if (idx < n1) {
        int j = idx & 7, n = (idx >> 3) & 1023, g = idx >> 13;
        float v = (n < 512) ? fc_w[n * 640 + g * 8 + j]
                            : fc_w[(n - 512) * 640 + 256 + g * 8 + j];
        Wp1[idx] = f2bf(v);
    } else {
        int k = idx - n1;
        if (k < 16 * 512 * 8) {
            int j = k & 7, n = (k >> 3) & 511, g = k >> 12;
            Wp3[k] = f2bf(fc_w[n * 640 + 512 + g * 8 + j]);
        }
    }
}

// ---------------- Kernel 1: P1 = W1*atom + b, P2 = W2*atom, stored PACKED (bf16) ---
// P row (1024 ushorts): [0:512) = P1 packed (packAddr8), [512:1024) = P2 packed.
__global__ __launch_bounds__(512, 2) void gemm_p(
    const float* __restrict__ atom, const float* __restrict__ fc_b,
    const unsigned short* __restrict__ Wp1, unsigned short* __restrict__ P)
{
    __shared__ unsigned short sA[128 * 256];   // 64KB, swizzled bf16 A-tile
    const int tid = threadIdx.x;
    const int r0 = blockIdx.x * 128;
    const int cb = blockIdx.y;                 // 0: W1 half (+bias), 1: W2 half

    #pragma unroll
    for (int s = 0; s < 8; ++s) {
        int G = tid + s * 512;
        int row = G >> 5, gc = G & 31;
        int grow = r0 + row;
        uint4 pk;
        if (grow < N_ATOMS) {
            const float4* src = reinterpret_cast<const float4*>(atom + (size_t)grow * 256 + gc * 8);
            float4 v0 = src[0], v1 = src[1];
            pk.x = pkbf(v0.x, v0.y); pk.y = pkbf(v0.z, v0.w);
            pk.z = pkbf(v1.x, v1.y); pk.w = pkbf(v1.z, v1.w);
        } else {
            pk = make_uint4(0u, 0u, 0u, 0u);
        }
        *reinterpret_cast<uint4*>(&sA[row * 256 + ((gc ^ (row & 7)) << 3)]) = pk;
    }
    __syncthreads();

    const int lane = tid & 63, wave = tid >> 6;
    const int wr = wave >> 2, wcc = wave & 3;
    const int l15 = lane & 15, l16 = lane >> 4;

    f32x4 acc[4][8];
    #pragma unroll
    for (int mt = 0; mt < 4; ++mt)
        #pragma unroll
        for (int nt = 0; nt < 8; ++nt) acc[mt][nt] = f32x4{0.f, 0.f, 0.f, 0.f};

    #pragma unroll
    for (int ks = 0; ks < 8; ++ks) {
        bf16x8 af[4];
        #pragma unroll
        for (int mt = 0; mt < 4; ++mt) {
            int row = wr * 64 + mt * 16 + l15;
            int g = ks * 4 + l16;
            af[mt] = *reinterpret_cast<const bf16x8*>(&sA[row * 256 + ((g ^ (row & 7)) << 3)]);
        }
        bf16x8 bfr[8];
        #pragma unroll
        for (int nt = 0; nt < 8; ++nt) {
            int col = cb * 512 + wcc * 128 + nt * 16 + l15;
            bfr[nt] = *reinterpret_cast<const bf16x8*>(&Wp1[((size_t)(ks * 4 + l16) * 1024 + col) * 8]);
        }
        #pragma unroll
        for (int mt = 0; mt < 4; ++mt)
            #pragma unroll
            for (int nt = 0; nt < 8; ++nt)
                acc[mt][nt] = __builtin_amdgcn_mfma_f32_16x16x32_bf16(af[mt], bfr[nt], acc[mt][nt], 0, 0, 0);
    }

    // epilogue: paired bf16 writes into packed layout
    #pragma unroll
    for (int np = 0; np < 4; ++np) {
        int zc0 = wcc * 128 + np * 32 + l15;     // nt = 2*np ; zc1 = zc0 + 16
        float b0 = (cb == 0) ? fc_b[zc0] : 0.f;
        float b1 = (cb == 0) ? fc_b[zc0 + 16] : 0.f;
        int pa = cb * 512 + packAddr8(zc0);      // even; zc0+16 lands at pa+1
        #pragma unroll
        for (int mt = 0; mt < 4; ++mt) {
            #pragma unroll
            for (int j = 0; j < 4; ++j) {
                int row = r0 + wr * 64 + mt * 16 + l16 * 4 + j;
                if (row < N_ATOMS)
                    *reinterpret_cast<unsigned*>(&P[(size_t)row * 1024 + pa]) =
                        pkbf(acc[mt][2 * np][j] + b0, acc[mt][2 * np + 1][j] + b1);
            }
        }
    }
}

// ---------------- Kernel 2: fused bond-GEMM + gather-add + LN1 + gate*core + mean + LN2 + residual
// 512 threads = 8 waves; 4 atoms (48 rows). Wave wc owns 32 gate cols + 32 core cols.
// acc is INITIALIZED with P1+P2 before the GEMM (MFMA accumulates bond@W3 on top) -> no spill.
__global__ __launch_bounds__(512, 4) void fused_conv(
    const float* __restrict__ atom, const float* __restrict__ bond,
    const int* __restrict__ nbr, const unsigned short* __restrict__ P,
    const unsigned short* __restrict__ Wp3,
    const float* __restrict__ ln1_g, const float* __restrict__ ln1_b,
    const float* __restrict__ ln2_g, const float* __restrict__ ln2_b,
    float* __restrict__ out)
{
    __shared__ unsigned short sA[48 * 128];              // 12KB bond tile (bf16, swizzled)
    __shared__ float sRed[2][48][9];                     // padded wave-partials
    __shared__ float2 sStat[48];                         // {rs*L2E, mu*rs*L2E} per row
    __shared__ float sO[4][256];                         // per-atom sum of gate*softplus (log2-scaled)

    const int tid = threadIdx.x;
    const int i0 = blockIdx.x * 4;                       // 7500 blocks exact
    const int lane = tid & 63, wc = tid >> 6;
    const int l15 = lane & 15, l16 = lane >> 4;
    const float L2E = 1.4426950408889634f;

    { float* so = &sO[0][0]; so[tid] = 0.f; so[tid + 512] = 0.f; }

    // ---- 1) neighbor indices FIRST
    int4 nbq0 = *reinterpret_cast<const int4*>(&nbr[i0 * 12 +      l16 * 4]);
    int4 nbq1 = *reinterpret_cast<const int4*>(&nbr[i0 * 12 + 16 + l16 * 4]);
    int4 nbq2 = *reinterpret_cast<const int4*>(&nbr[i0 * 12 + 32 + l16 * 4]);

    // ---- 2) bond loads
    float4 bv[2][2];
    #pragma unroll
    for (int s = 0; s < 2; ++s) {
        int G = tid + s * 512;
        if (G < 768) {
            int row = G >> 4, gc = G & 15;
            const float4* src = reinterpret_cast<const float4*>(bond + (size_t)(i0 * 12 + row) * 128 + gc * 8);
            bv[s][0] = src[0]; bv[s][1] = src[1];
        }
    }

    // ---- 3) ALL P2 gathers (12) + P1 (3). 32-bit addressing; consumed before the GEMM.
    const char* Pb = reinterpret_cast<const char*>(P);
    const unsigned cOff = (unsigned)(wc * 128 + l15 * 8);      // byte offset within packed half-row
    uint2 p2q[12];
    {
        const int* n0 = reinterpret_cast<const int*>(&nbq0);
        const int* n1 = reinterpret_cast<const int*>(&nbq1);
        const int* n2 = reinterpret_cast<const int*>(&nbq2);
        #pragma unroll
        for (int j = 0; j < 4; ++j) {
            p2q[j]     = *reinterpret_cast<const uint2*>(Pb + ((unsigned)n0[j] * 2048u + 1024u + cOff));
            p2q[4 + j] = *reinterpret_cast<const uint2*>(Pb + ((unsigned)n1[j] * 2048u + 1024u + cOff));
            p2q[8 + j] = *reinterpret_cast<const uint2*>(Pb + ((unsigned)n2[j] * 2048u + 1024u + cOff));
        }
    }
    uint2 p1q[3];
    #pragma unroll
    for (int mt = 0; mt < 3; ++mt) {
        unsigned li = (unsigned)((mt * 16 + l16 * 4) / 12);    // j-quads never cross atoms
        p1q[mt] = *reinterpret_cast<const uint2*>(Pb + (((unsigned)i0 + li) * 2048u + cOff));
    }

    // ---- 4) convert + stage bond tile (waits on bond only; gathers stay in flight)
    #pragma unroll
    for (int s = 0; s < 2; ++s) {
        int G = tid + s * 512;
        if (G < 768) {
            int row = G >> 4, gc = G & 15;
            uint4 pk;
            pk.x = pkbf(bv[s][0].x, bv[s][0].y); pk.y = pkbf(bv[s][0].z, bv[s][0].w);
            pk.z = pkbf(bv[s][1].x, bv[s][1].y); pk.w = pkbf(bv[s][1].z, bv[s][1].w);
            *reinterpret_cast<uint4*>(&sA[row * 128 + ((gc ^ (row & 7)) << 3)]) = pk;
        }
    }

    // ---- 5) acc := P1 + P2 (gathered values die here, before the GEMM)
    f32x4 acc[3][4];
    #pragma unroll
    for (int mt = 0; mt < 3; ++mt) {
        uint2 c1 = p1q[mt];
        float p1v[4] = { bflo(c1.x), bfhi(c1.x), bflo(c1.y), bfhi(c1.y) };
        #pragma unroll
        for (int j = 0; j < 4; ++j) {
            uint2 c2 = p2q[mt * 4 + j];
            acc[mt][0][j] = p1v[0] + bflo(c2.x);
            acc[mt][1][j] = p1v[1] + bfhi(c2.x);
            acc[mt][2][j] = p1v[2] + bflo(c2.y);
            acc[mt][3][j] = p1v[3] + bfhi(c2.y);
        }
    }
    __syncthreads();

    // ---- GEMM: acc += [48,128(bond)] @ Wp3; wave's cols = 32 gate (nt 0,1) + 32 core (nt 2,3)
    #pragma unroll
    for (int ks = 0; ks < 4; ++ks) {
        bf16x8 af[3];
        #pragma unroll
        for (int mt = 0; mt < 3; ++mt) {
            int row = mt * 16 + l15;
            int g = ks * 4 + l16;
            af[mt] = *reinterpret_cast<const bf16x8*>(&sA[row * 128 + ((g ^ (row & 7)) << 3)]);
        }
        bf16x8 bfr[4];
        #pragma unroll
        for (int nt = 0; nt < 4; ++nt) {
            int col = (nt < 2) ? (wc * 32 + nt * 16 + l15)
                               : (256 + wc * 32 + (nt - 2) * 16 + l15);
            bfr[nt] = *reinterpret_cast<const bf16x8*>(&Wp3[((size_t)(ks * 4 + l16) * 512 + col) * 8]);
        }
        #pragma unroll
        for (int mt = 0; mt < 3; ++mt)
            #pragma unroll
            for (int nt = 0; nt < 4; ++nt)
                acc[mt][nt] = __builtin_amdgcn_mfma_f32_16x16x32_bf16(af[mt], bfr[nt], acc[mt][nt], 0, 0, 0);
    }

    // ---- pass 1: LN1 partial stats (stats only; adds already folded into acc) ----
    #pragma unroll
    for (int mt = 0; mt < 3; ++mt) {
        #pragma unroll
        for (int j = 0; j < 4; ++j) {
            const int row = mt * 16 + l16 * 4 + j;
            float z0 = acc[mt][0][j], z1 = acc[mt][1][j];
            float z2 = acc[mt][2][j], z3 = acc[mt][3][j];
            float s = (z0 + z1) + (z2 + z3);
            float q = fmaf(z0, z0, fmaf(z1, z1, fmaf(z2, z2, z3 * z3)));
            s = rowsum16(s);
            q = rowsum16(q);
            if (l15 == 0) { sRed[0][row][wc] = s; sRed[1][row][wc] = q; }
        }
    }

    // LN1 affine params (log2e-folded biases): latency hides under barrier+mini-reduce
    float g1[2], gC[2], l2b1[2], l2bC[2];
    #pragma unroll
    for (int nt = 0; nt < 2; ++nt) {
        int a = wc * 32 + nt * 16 + l15;
        g1[nt] = ln1_g[a];       l2b1[nt] = ln1_b[a] * L2E;
        gC[nt] = ln1_g[256 + a]; l2bC[nt] = ln1_b[256 + a] * L2E;
    }
    __syncthreads();

    // ---- mini-reduce: fold 8 wave-partials -> {rs*L2E, mu*rs*L2E} ----
    if (tid < 48) {
        float s4 = 0.f, q4 = 0.f;
        #pragma unroll
        for (int w = 0; w < 8; ++w) { s4 += sRed[0][tid][w]; q4 += sRed[1][tid][w]; }
        float mu = s4 * (1.f / 512.f);
        float var = q4 * (1.f / 512.f) - mu * mu;
        float rs = __builtin_amdgcn_rsqf(var + 1e-5f) * L2E;
        sStat[tid] = make_float2(rs, mu * rs);
    }
    __syncthreads();

    // ---- pass 2: log2-domain sigmoid*softplus via raw v_exp/v_log; ln2 & 1/12 cancel in LN2 ----
    #pragma unroll
    for (int mt = 0; mt < 3; ++mt) {
        const int li = (mt * 16 + l16 * 4) / 12;
        float2 st[4];
        #pragma unroll
        for (int j = 0; j < 4; ++j) st[j] = sStat[mt * 16 + l16 * 4 + j];
        #pragma unroll
        for (int nt = 0; nt < 2; ++nt) {
            float tq = 0.f;
            #pragma unroll
            for (int j = 0; j < 4; ++j) {
                float ug = fmaf(fmaf(acc[mt][nt][j],     st[j].x, -st[j].y), g1[nt], l2b1[nt]);
                float uc = fmaf(fmaf(acc[mt][nt + 2][j], st[j].x, -st[j].y), gC[nt], l2bC[nt]);
                float gt  = __builtin_amdgcn_rcpf(1.f + fexp2(-ug));
                float sp2 = flog2(1.f + fexp2(uc));
                tq = fmaf(gt, sp2, tq);
            }
            atomicAdd(&sO[li][wc * 32 + nt * 16 + l15], tq);   // 3 contributors per address
        }
    }
    __syncthreads();

    // ---- LN2 + residual (scale-invariant): waves 0..3, one atom each ----
    if (wc < 4) {
        const int gi = i0 + wc;
        float v[4]; float s = 0.f, q = 0.f;
        #pragma unroll
        for (int qd = 0; qd < 4; ++qd) {
            v[qd] = sO[wc][lane + qd * 64];
            s += v[qd]; q = fmaf(v[qd], v[qd], q);
        }
        #pragma unroll
        for (int msk = 1; msk <= 32; msk <<= 1) {
            s += __shfl_xor(s, msk, 64);
            q += __shfl_xor(q, msk, 64);
        }
        float mu = s * (1.f / 256.f);
        float var = q * (1.f / 256.f) - mu * mu;
        float rstd = __builtin_amdgcn_rsqf(var + 1e-5f);
        #pragma unroll
        for (int qd = 0; qd < 4; ++qd) {
            int a = lane + qd * 64;
            out[(size_t)gi * 256 + a] = atom[(size_t)gi * 256 + a]
                                      + (v[qd] - mu) * rstd * ln2_g[a] + ln2_b[a];
        }
    }
}

extern "C" void kernel_launch(void* const* d_in, const int* in_sizes, int n_in,
                              void* d_out, int out_size, void* d_ws, size_t ws_size,
                              hipStream_t stream) {
    const float* atom  = (const float*)d_in[0];
    const float* bond  = (const float*)d_in[1];
    const float* fc_w  = (const float*)d_in[2];
    const float* fc_b  = (const float*)d_in[3];
    const float* ln1_g = (const float*)d_in[4];
    const float* ln1_b = (const float*)d_in[5];
    const float* ln2_g = (const float*)d_in[6];
    const float* ln2_b = (const float*)d_in[7];
    const int*   nbr   = (const int*)d_in[8];

    char* ws = (char*)d_ws;
    unsigned short* P   = (unsigned short*)ws;                          // 61,440,000 B
    unsigned short* Wp1 = (unsigned short*)(ws + 61440000);             // 524,288 B
    unsigned short* Wp3 = (unsigned short*)(ws + 61440000 + 524288);    // 131,072 B
    float* outp = (float*)d_out;

    hipLaunchKernelGGL(pack_weights, dim3(1280), dim3(256), 0, stream, fc_w, Wp1, Wp3);
    hipLaunchKernelGGL(gemm_p, dim3(235, 2), dim3(512), 0, stream, atom, fc_b, Wp1, P);
    hipLaunchKernelGGL(fused_conv, dim3(7500), dim3(512), 0, stream,
                       atom, bond, nbr, P, Wp3, ln1_g, ln1_b, ln2_g, ln2_b, outp);
}